// Round 1
// baseline (138.530 us; speedup 1.0000x reference)
//
#include <hip/hip_runtime.h>
#include <math.h>

// StyleGAN2 2x upsample blur (upfirdn2d, up=2, f=[1,3,3,1], gain=4).
// Separable per-axis weights g=[0.25,0.75,0.75,0.25]:
//   out[2i]   = 0.25*X[i-1] + 0.75*X[i]
//   out[2i+1] = 0.75*X[i]   + 0.25*X[i+1]
// (out-of-range input rows/cols contribute 0)

__global__ __launch_bounds__(256) void blur_up2_kernel(
    const float* __restrict__ x, float* __restrict__ out,
    int H, int W, int Ho, int Wo) {
    int idx = blockIdx.x * 256 + threadIdx.x;
    int hw = Ho * Wo;
    if (idx >= hw) return;
    int nc = blockIdx.y;

    int ox = idx % Wo;
    int oy = idx / Wo;
    int i = oy >> 1, j = ox >> 1;

    int iy0, iy1; float wy0, wy1;
    if (oy & 1) { iy0 = i;     wy0 = 0.75f; iy1 = i + 1; wy1 = 0.25f; }
    else        { iy0 = i - 1; wy0 = 0.25f; iy1 = i;     wy1 = 0.75f; }
    int ix0, ix1; float wx0, wx1;
    if (ox & 1) { ix0 = j;     wx0 = 0.75f; ix1 = j + 1; wx1 = 0.25f; }
    else        { ix0 = j - 1; wx0 = 0.25f; ix1 = j;     wx1 = 0.75f; }

    const float* xp = x + (size_t)nc * H * W;

    bool y0ok = (iy0 >= 0) & (iy0 < H);
    bool y1ok = (iy1 >= 0) & (iy1 < H);
    bool x0ok = (ix0 >= 0) & (ix0 < W);
    bool x1ok = (ix1 >= 0) & (ix1 < W);

    float a00 = (y0ok && x0ok) ? xp[iy0 * W + ix0] : 0.0f;
    float a01 = (y0ok && x1ok) ? xp[iy0 * W + ix1] : 0.0f;
    float a10 = (y1ok && x0ok) ? xp[iy1 * W + ix0] : 0.0f;
    float a11 = (y1ok && x1ok) ? xp[iy1 * W + ix1] : 0.0f;

    float r = wy0 * (wx0 * a00 + wx1 * a01) + wy1 * (wx0 * a10 + wx1 * a11);
    out[(size_t)nc * hw + idx] = r;
}

extern "C" void kernel_launch(void* const* d_in, const int* in_sizes, int n_in,
                              void* d_out, int out_size, void* d_ws, size_t ws_size,
                              hipStream_t stream) {
    const float* x = (const float*)d_in[0];
    float* out = (float*)d_out;

    // Reference shapes: x is [4, 64, 256, 256] fp32.
    const int H = 256, W = 256;
    int NC = in_sizes[0] / (H * W);  // 256

    // Output spatial size derived from out_size (handles 511 or 512 per side).
    int hw_out = out_size / NC;
    int Wo = (int)(sqrt((double)hw_out) + 0.5);
    int Ho = hw_out / Wo;

    dim3 block(256);
    dim3 grid((hw_out + 255) / 256, NC);
    blur_up2_kernel<<<grid, block, 0, stream>>>(x, out, H, W, Ho, Wo);
}

// Round 2
// 130.792 us; speedup vs baseline: 1.0592x; 1.0592x over previous
//
#include <hip/hip_runtime.h>
#include <math.h>

// StyleGAN2 2x upsample blur (upfirdn2d, up=2, f=[1,3,3,1], gain=4).
// Separable per-axis weights g=[0.25,0.75,0.75,0.25]:
//   out[2i]   = 0.25*X[i-1] + 0.75*X[i]
//   out[2i+1] = 0.75*X[i]   + 0.25*X[i+1]
//
// Each thread computes a 4x4 output tile (rows oy0..oy0+3, cols ox0..ox0+3)
// from a 4x4 input patch (rows ib-1..ib+2, cols jb-1..jb+2), separable:
// vertical blend first (4x4 -> 4 rows), then horizontal (-> 4 cols).
// Block = (64,4): 64 x-tiles * 4 y-tiles => 256x16 output per block.

__global__ __launch_bounds__(256) void blur_up2_kernel(
    const float* __restrict__ x, float* __restrict__ out,
    int H, int W, int Ho, int Wo) {
    int tx = threadIdx.x;                       // 0..63 -> x-tile in block
    int ty = threadIdx.y;                       // 0..3  -> y-tile in block
    int ox0 = blockIdx.x * 256 + tx * 4;
    int oy0 = (blockIdx.y * 4 + ty) * 4;
    int nc = blockIdx.z;
    if (ox0 >= Wo || oy0 >= Ho) return;

    int jb = ox0 >> 1;   // input col base (outputs 4t..4t+3 need cols jb-1..jb+2)
    int ib = oy0 >> 1;   // input row base (rows ib-1..ib+2)

    const float* xp = x + (size_t)nc * H * W;

    // Load 4x4 input patch with zero padding outside [0,H)x[0,W).
    float a[4][4];
#pragma unroll
    for (int r = 0; r < 4; ++r) {
        int iy = ib - 1 + r;
        bool yok = (iy >= 0) & (iy < H);
        const float* rowp = xp + iy * W;
#pragma unroll
        for (int c = 0; c < 4; ++c) {
            int ix = jb - 1 + c;
            bool ok = yok & (ix >= 0) & (ix < W);
            a[r][c] = ok ? rowp[ix] : 0.0f;
        }
    }

    // Vertical blend: out rows 2*(ib+p), 2*(ib+p)+1 for p=0,1.
    // v[2p][c]   = 0.25*a[p][c]   + 0.75*a[p+1][c]
    // v[2p+1][c] = 0.75*a[p+1][c] + 0.25*a[p+2][c]
    float v[4][4];
#pragma unroll
    for (int p = 0; p < 2; ++p) {
#pragma unroll
        for (int c = 0; c < 4; ++c) {
            v[2 * p][c]     = 0.25f * a[p][c]     + 0.75f * a[p + 1][c];
            v[2 * p + 1][c] = 0.75f * a[p + 1][c] + 0.25f * a[p + 2][c];
        }
    }

    // Horizontal blend + store. v cols map to input cols jb-1+c.
    size_t obase = (size_t)nc * Ho * Wo;
#pragma unroll
    for (int r = 0; r < 4; ++r) {
        int oy = oy0 + r;
        if (oy < Ho) {
            float o0 = 0.25f * v[r][0] + 0.75f * v[r][1];
            float o1 = 0.75f * v[r][1] + 0.25f * v[r][2];
            float o2 = 0.25f * v[r][1] + 0.75f * v[r][2];
            float o3 = 0.75f * v[r][2] + 0.25f * v[r][3];
            float* op = out + obase + (size_t)oy * Wo + ox0;
            if (ox0 + 4 <= Wo) {
                op[0] = o0; op[1] = o1; op[2] = o2; op[3] = o3;
            } else {
                int rem = Wo - ox0;
                if (rem > 0) op[0] = o0;
                if (rem > 1) op[1] = o1;
                if (rem > 2) op[2] = o2;
            }
        }
    }
}

extern "C" void kernel_launch(void* const* d_in, const int* in_sizes, int n_in,
                              void* d_out, int out_size, void* d_ws, size_t ws_size,
                              hipStream_t stream) {
    const float* x = (const float*)d_in[0];
    float* out = (float*)d_out;

    const int H = 256, W = 256;
    int NC = in_sizes[0] / (H * W);  // 256

    int hw_out = out_size / NC;
    int Wo = (int)(sqrt((double)hw_out) + 0.5);
    int Ho = hw_out / Wo;

    dim3 block(64, 4);
    dim3 grid((Wo + 255) / 256, (Ho + 15) / 16, NC);
    blur_up2_kernel<<<grid, block, 0, stream>>>(x, out, H, W, Ho, Wo);
}